// Round 18
// baseline (34.205 us; speedup 1.0000x reference)
//
#include <hip/hip_runtime.h>
#include <hip/hip_bf16.h>
#include <stdint.h>

#define BB 64
#define TT 4096
#define NS 32
#define DD 64
#define CH 256     // chunks per subject
#define CL 16      // chunk length
#define WU 8       // warmup steps (Birkhoff tau~0.15/step -> ~3e-7 after 8)
#define NSTEPS (WU + CL)
#define LOG2PI 1.8378770664093453f
#define LN2F 0.6931471805599453f
#define FLT_MIN_NORM 1.175494350822288e-38f

typedef float f32x16 __attribute__((ext_vector_type(16)));
typedef __bf16 bf16x8 __attribute__((ext_vector_type(8)));

__device__ __forceinline__ uint32_t cvt_pk_bf16(float lo, float hi) {
  uint32_t d;
  asm("v_cvt_pk_bf16_f32 %0, %1, %2" : "=v"(d) : "v"(lo), "v"(hi));
  return d;
}

// max over all 64 lanes; result valid in lane 63
__device__ __forceinline__ float dpp_max64(float v) {
  float r = v; int x;
  x = __builtin_amdgcn_update_dpp(__float_as_int(r), __float_as_int(r), 0x111, 0xF, 0xF, false); r = fmaxf(r, __int_as_float(x));
  x = __builtin_amdgcn_update_dpp(__float_as_int(r), __float_as_int(r), 0x112, 0xF, 0xF, false); r = fmaxf(r, __int_as_float(x));
  x = __builtin_amdgcn_update_dpp(__float_as_int(r), __float_as_int(r), 0x114, 0xF, 0xF, false); r = fmaxf(r, __int_as_float(x));
  x = __builtin_amdgcn_update_dpp(__float_as_int(r), __float_as_int(r), 0x118, 0xF, 0xF, false); r = fmaxf(r, __int_as_float(x));
  x = __builtin_amdgcn_update_dpp(__float_as_int(r), __float_as_int(r), 0x142, 0xF, 0xF, false); r = fmaxf(r, __int_as_float(x));
  x = __builtin_amdgcn_update_dpp(__float_as_int(r), __float_as_int(r), 0x143, 0xF, 0xF, false); r = fmaxf(r, __int_as_float(x));
  return r;
}

// slot bijection shared by: MFMA C-row layout (HW-verified), scan A^T-frag,
// scan B-frag, blin state pairing, pivec reset.
//   state(h, r) = (r&3) + 8*((r>>2)&1) + 4*h + 16*(r>>3),  r in [0,16)

// ---------------- K1: preprocess (R14-exact)
__global__ __launch_bounds__(1024) void k_pre(
    const float* __restrict__ tm, const float* __restrict__ sp,
    const float* __restrict__ mus, const float* __restrict__ lv,
    float* __restrict__ pivec, uint32_t* __restrict__ Wp,
    float* __restrict__ bias, uint32_t* __restrict__ Af)
{
  __shared__ float As[32][32];
  const int tid = threadIdx.x;       // 0..1023
  const int row = tid >> 5;          // 0..31
  const int col = tid & 31;          // 0..31

  {
    float v = tm[row * 32 + col];
    float m = v;
    #pragma unroll
    for (int mask = 16; mask; mask >>= 1) m = fmaxf(m, __shfl_xor(m, mask));
    float e = __expf(v - m);
    float s = e;
    #pragma unroll
    for (int mask = 16; mask; mask >>= 1) s += __shfl_xor(s, mask);
    As[row][col] = e / s;
  }

  if (tid < 32) {
    float v = sp[tid];
    float m = v;
    #pragma unroll
    for (int mask = 16; mask; mask >>= 1) m = fmaxf(m, __shfl_xor(m, mask));
    float e = __expf(v - m);
    float s = e;
    #pragma unroll
    for (int mask = 16; mask; mask >>= 1) s += __shfl_xor(s, mask);
    pivec[tid] = e / s;
  }

  #pragma unroll
  for (int hh = 0; hh < 2; ++hh) {
    int d = col + (hh << 5);             // 0..63
    float iv = __expf(-lv[row * 64 + d]);
    uint32_t w = cvt_pk_bf16(-0.5f * iv, mus[row * 64 + d] * iv);
    int kk = d >> 3, h2 = (d >> 2) & 1, j = d & 3;
    Wp[(((row << 1) + h2) * 8 + kk) * 4 + j] = w;
  }

  {
    float s2 = 0.f, slv = 0.f;
    #pragma unroll
    for (int h = 0; h < 2; ++h) {
      int d = col + h * 32;
      float m_ = mus[row * 64 + d];
      float l_ = lv[row * 64 + d];
      s2 = fmaf(m_ * m_, __expf(-l_), s2);
      slv += l_;
    }
    #pragma unroll
    for (int mask = 16; mask; mask >>= 1) {
      s2  += __shfl_xor(s2, mask);
      slv += __shfl_xor(slv, mask);
    }
    if (col == 0) bias[row] = -0.5f * (s2 + slv + (float)DD * LOG2PI);
  }

  __syncthreads();

  if (tid < 512) {
    int l = tid >> 3, s = tid & 7;
    int m = s >> 2, p = s & 3;
    int j = l & 31, hh = l >> 5;
    int r0 = 2 * p, r1 = r0 + 1;
    int s0 = (r0 & 3) + 8 * ((r0 >> 2) & 1) + 4 * hh + 16 * m;
    int s1 = (r1 & 3) + 8 * ((r1 >> 2) & 1) + 4 * hh + 16 * m;
    Af[(l << 3) + (m << 2) + p] = cvt_pk_bf16(As[s0][j], As[s1][j]);
  }
}

// ---------------- K2: FUSED emission + scan (R18: 8 waves per block)
// Block = (subject b, 512-row superblock cb) = 32 chunks of 16.
// Emis phase: 8 waves x 17 windows (16 real + warmup overlap) -> blin in LDS
// (544 rows x 64 B, slot-XOR swizzle). Scan phase: wave 0, 32 chunks from LDS.
// blin NEVER touches HBM. Same work as R14/R17; 2x waves for latency hiding.
__global__ __launch_bounds__(512) void k_fused(
    const float* __restrict__ Xg,
    const uint32_t* __restrict__ Wp,
    const float* __restrict__ bias,
    const uint32_t* __restrict__ Af,
    const float* __restrict__ pivec,
    float* __restrict__ out,
    float* __restrict__ Mc)
{
  __shared__ uint32_t blinL[544 * 16];   // 34 KB
  __shared__ float KcL[32];
  const int tid = threadIdx.x;
  const int l   = tid & 63;
  const int wv  = tid >> 6;            // wave 0..7
  const int g   = blockIdx.x;          // 0..511
  const int b   = g >> 3;
  const int cb  = g & 7;
  const int t0  = cb << 9;             // superblock start t
  const int n   = l & 31;
  const int h   = l >> 5;

  // hoisted emis B-frags + bias
  uint4 wf[8];
  const uint4* wp4 = (const uint4*)(Wp + ((n << 1) + h) * 32);
  #pragma unroll
  for (int kk = 0; kk < 8; ++kk) wf[kk] = wp4[kk];
  const float bn = bias[n];

  // ---- emis phase: windows wi=0 (warmup overlap) .. 16, split across 8 waves
  for (int wi = wv; wi < 17; wi += 8) {
    if (cb == 0 && wi == 0) continue;            // chunk-0 clamp handles it
    const int wbase = t0 - 32 + (wi << 5);       // global t of window row 0
    const float* xr = Xg + (size_t)(b * TT + wbase + n) * DD + (h << 2);

    f32x16 acc;
    #pragma unroll
    for (int r = 0; r < 16; ++r) acc[r] = 0.0f;

    #pragma unroll
    for (int kk = 0; kk < 8; ++kk) {
      float4 x4 = *(const float4*)(xr + (kk << 3));
      uint4 au;
      au.x = cvt_pk_bf16(x4.x * x4.x, x4.x);
      au.y = cvt_pk_bf16(x4.y * x4.y, x4.y);
      au.z = cvt_pk_bf16(x4.z * x4.z, x4.z);
      au.w = cvt_pk_bf16(x4.w * x4.w, x4.w);
      bf16x8 af = __builtin_bit_cast(bf16x8, au);
      bf16x8 bf = __builtin_bit_cast(bf16x8, wf[kk]);
      acc = __builtin_amdgcn_mfma_f32_32x32x16_bf16(af, bf, acc, 0, 0, 0);
    }

    float lb[16];
    float m0 = -1e30f, m1 = -1e30f;
    #pragma unroll
    for (int r = 0; r < 16; ++r) {
      lb[r] = acc[r] + bn;
      if (r < 8) m0 = fmaxf(m0, lb[r]); else m1 = fmaxf(m1, lb[r]);
    }
    m0 = dpp_max64(m0);
    m1 = dpp_max64(m1);
    const float Km0 = __int_as_float(__builtin_amdgcn_readlane(__float_as_int(m0), 63));
    const float Km1 = __int_as_float(__builtin_amdgcn_readlane(__float_as_int(m1), 63));
    if (wi >= 1 && l == 0) {
      KcL[((wi - 1) << 1)]     = Km0;
      KcL[((wi - 1) << 1) + 1] = Km1;
    }

    const int rb = wi << 5;                      // LDS row of window row 0
    #pragma unroll
    for (int r = 0; r < 16; ++r) {
      float e = __expf(lb[r] - ((r < 8) ? Km0 : Km1));
      int nb = __builtin_amdgcn_update_dpp(0, __float_as_int(e), 0xB1, 0xF, 0xF, true); // lane^1
      uint32_t pk = cvt_pk_bf16(e, __int_as_float(nb));   // lo = even n, hi = odd n
      const int ldsrow = rb + (r & 3) + ((r >> 2) << 3) + (h << 2);
      if ((l & 1) == 0)
        blinL[ldsrow * 16 + ((n >> 1) ^ (((ldsrow >> 4) & 7) << 1))] = pk;
    }
  }
  __syncthreads();
  if (wv != 0) return;

  // ---- scan phase (wave 0 only): 32 chunks, lane col = chunk
  const int col = n;
  const int c   = (cb << 5) + col;               // chunk 0..255
  const bool isC0 = (cb == 0) && (col == 0);

  const uint4 af0u = *(const uint4*)(Af + (l << 3));
  const uint4 af1u = *(const uint4*)(Af + (l << 3) + 4);
  const bf16x8 af0 = __builtin_bit_cast(bf16x8, af0u);
  const bf16x8 af1 = __builtin_bit_cast(bf16x8, af1u);

  const float KcH = KcL[col];
  const int outbase = b * TT + (c << 4);

  f32x16 zv;
  #pragma unroll
  for (int r = 0; r < 16; ++r) zv[r] = 0.0f;

  float v[16];
  #pragma unroll
  for (int r = 0; r < 16; ++r) v[r] = 1.0f;
  float S = 0.0f, sPrev = 1.0f;

  #pragma unroll
  for (int q = 0; q < NSTEPS; ++q) {
    float sP = fmaxf(sPrev, FLT_MIN_NORM);
    int e = ((__float_as_int(sP) >> 23) & 0xFF) - 126;
    float rf = __int_as_float((127 - e) << 23);
    if (q >= WU) {
      float outv = __log2f(sP) * LN2F + S;
      if (q == WU) { if (h == 0) Mc[(b << 8) + c] = outv; }
      else         { if (h == 0) out[outbase + q - WU - 1] = outv; }
      S += KcH + (float)e * LN2F;
    } else {
      S += (float)e * LN2F;
    }

    // read b_t row from LDS (logical slots {h2,h2+1, +4, +8, +12})
    int ldsrow = 24 + (col << 4) + q;
    if (cb == 0 && ldsrow < 32) ldsrow = 32;     // chunk-0 clamp
    const int swz = ((ldsrow >> 4) & 7) << 1;
    const uint32_t* p = blinL + ldsrow * 16;
    const int h2 = h << 1;
    uint2 u0 = *(const uint2*)(p + (h2 ^ swz));
    uint2 u1 = *(const uint2*)(p + ((h2 + 4) ^ swz));
    uint2 u2 = *(const uint2*)(p + ((h2 + 8) ^ swz));
    uint2 u3 = *(const uint2*)(p + ((h2 + 12) ^ swz));
    uint32_t CUR[8];
    CUR[0] = u0.x; CUR[1] = u0.y; CUR[2] = u1.x; CUR[3] = u1.y;
    CUR[4] = u2.x; CUR[5] = u2.y; CUR[6] = u3.x; CUR[7] = u3.y;

    float vr[16];
    #pragma unroll
    for (int r = 0; r < 16; ++r) vr[r] = v[r] * rf;
    uint32_t p2[8];
    #pragma unroll
    for (int i = 0; i < 8; ++i) p2[i] = cvt_pk_bf16(vr[2*i], vr[2*i+1]);
    uint4 b0u; b0u.x = p2[0]; b0u.y = p2[1]; b0u.z = p2[2]; b0u.w = p2[3];
    uint4 b1u; b1u.x = p2[4]; b1u.y = p2[5]; b1u.z = p2[6]; b1u.w = p2[7];
    f32x16 acc = __builtin_amdgcn_mfma_f32_32x32x16_bf16(af0, __builtin_bit_cast(bf16x8, b0u), zv, 0, 0, 0);
    acc = __builtin_amdgcn_mfma_f32_32x32x16_bf16(af1, __builtin_bit_cast(bf16x8, b1u), acc, 0, 0, 0);

    #pragma unroll
    for (int i = 0; i < 8; ++i) {
      float blo = __int_as_float(CUR[i] << 16);
      float bhi = __int_as_float(CUR[i] & 0xFFFF0000u);
      float d0 = acc[2*i], d1 = acc[2*i+1];
      if (q == WU) { if (isC0) { d0 = vr[2*i]; d1 = vr[2*i+1]; } }
      v[2*i]   = d0 * blo;
      v[2*i+1] = d1 * bhi;
    }
    if (q == WU - 1) {
      if (isC0) {
        #pragma unroll
        for (int r = 0; r < 16; ++r)
          v[r] = pivec[(r & 3) + 8 * ((r >> 2) & 1) + (h << 2) + ((r >> 3) << 4)];
        S = 0.0f;
      }
    }
    float s8[8];
    #pragma unroll
    for (int i = 0; i < 8; ++i) s8[i] = v[2*i] + v[2*i+1];
    float s4a = s8[0] + s8[1], s4b = s8[2] + s8[3];
    float s4c = s8[4] + s8[5], s4d = s8[6] + s8[7];
    float s = (s4a + s4b) + (s4c + s4d);
    s += __shfl_xor(s, 32);
    sPrev = s;
  }

  {
    float sP = fmaxf(sPrev, FLT_MIN_NORM);
    if (h == 0) out[outbase + CL - 1] = __log2f(sP) * LN2F + S;
  }
}

// ---------------- K3: FUSED stitch + add (one block per subject)
__global__ __launch_bounds__(256) void k_post(
    float* __restrict__ out, const float* __restrict__ Mcc)
{
  __shared__ float DeltaL[256];
  __shared__ float wsum[4];
  const int b  = blockIdx.x;
  const int c  = threadIdx.x;     // 0..255 (4 waves)
  const int wv = c >> 6, ln = c & 63;
  float term = 0.0f;
  if (c > 0) term = out[b * TT + (c << 4) - 1] - Mcc[(b << 8) + c];
  for (int off = 1; off < 64; off <<= 1) {
    float up = __shfl_up(term, off);
    if (ln >= off) term += up;
  }
  if (ln == 63) wsum[wv] = term;
  __syncthreads();
  float add = 0.0f;
  for (int i = 0; i < wv; ++i) add += wsum[i];
  DeltaL[c] = term + add;
  __syncthreads();
  #pragma unroll
  for (int t = c; t < TT; t += 256)
    out[b * TT + t] += DeltaL[t >> 4];
}

extern "C" void kernel_launch(void* const* d_in, const int* in_sizes, int n_in,
                              void* d_out, int out_size, void* d_ws, size_t ws_size,
                              hipStream_t stream) {
  const float* X   = (const float*)d_in[0];
  const float* tm  = (const float*)d_in[1];
  const float* sp  = (const float*)d_in[2];
  const float* mus = (const float*)d_in[3];
  const float* lv  = (const float*)d_in[4];
  float* out = (float*)d_out;

  char* ws = (char*)d_ws;
  size_t off = 0;
  float* Mcc   = (float*)(ws + off); off += (size_t)BB * CH * 4;
  float* pivec = (float*)(ws + off); off += 256;
  uint32_t* Wp = (uint32_t*)(ws + off); off += (size_t)2048 * 4;
  float* bias  = (float*)(ws + off); off += 256;
  uint32_t* Af = (uint32_t*)(ws + off); off += (size_t)512 * 4;

  k_pre<<<dim3(1), dim3(1024), 0, stream>>>(tm, sp, mus, lv, pivec, Wp, bias, Af);
  k_fused<<<dim3(512), dim3(512), 0, stream>>>(X, Wp, bias, Af, pivec, out, Mcc);
  k_post<<<dim3(BB), dim3(256), 0, stream>>>(out, Mcc);
}

// Round 19
// 32.699 us; speedup vs baseline: 1.0460x; 1.0460x over previous
//
#include <hip/hip_runtime.h>
#include <hip/hip_bf16.h>
#include <stdint.h>

#define BB 64
#define TT 4096
#define NS 32
#define DD 64
#define CH 256     // chunks per subject
#define CL 16      // chunk length
#define WU 8       // warmup steps (Birkhoff tau~0.15/step -> ~3e-7 after 8)
#define NSTEPS (WU + CL)
#define LOG2PI 1.8378770664093453f
#define LN2F 0.6931471805599453f
#define FLT_MIN_NORM 1.175494350822288e-38f

typedef float f32x16 __attribute__((ext_vector_type(16)));
typedef __bf16 bf16x8 __attribute__((ext_vector_type(8)));

__device__ __forceinline__ uint32_t cvt_pk_bf16(float lo, float hi) {
  uint32_t d;
  asm("v_cvt_pk_bf16_f32 %0, %1, %2" : "=v"(d) : "v"(lo), "v"(hi));
  return d;
}

// max over all 64 lanes; result valid in lane 63
__device__ __forceinline__ float dpp_max64(float v) {
  float r = v; int x;
  x = __builtin_amdgcn_update_dpp(__float_as_int(r), __float_as_int(r), 0x111, 0xF, 0xF, false); r = fmaxf(r, __int_as_float(x));
  x = __builtin_amdgcn_update_dpp(__float_as_int(r), __float_as_int(r), 0x112, 0xF, 0xF, false); r = fmaxf(r, __int_as_float(x));
  x = __builtin_amdgcn_update_dpp(__float_as_int(r), __float_as_int(r), 0x114, 0xF, 0xF, false); r = fmaxf(r, __int_as_float(x));
  x = __builtin_amdgcn_update_dpp(__float_as_int(r), __float_as_int(r), 0x118, 0xF, 0xF, false); r = fmaxf(r, __int_as_float(x));
  x = __builtin_amdgcn_update_dpp(__float_as_int(r), __float_as_int(r), 0x142, 0xF, 0xF, false); r = fmaxf(r, __int_as_float(x));
  x = __builtin_amdgcn_update_dpp(__float_as_int(r), __float_as_int(r), 0x143, 0xF, 0xF, false); r = fmaxf(r, __int_as_float(x));
  return r;
}

// slot bijection shared by: MFMA C-row layout (HW-verified), scan A^T-frag,
// scan B-frag, blin state pairing, pivec reset.
//   state(h, r) = (r&3) + 8*((r>>2)&1) + 4*h + 16*(r>>3),  r in [0,16)

// ---------------- K1: preprocess (R14-exact)
__global__ __launch_bounds__(1024) void k_pre(
    const float* __restrict__ tm, const float* __restrict__ sp,
    const float* __restrict__ mus, const float* __restrict__ lv,
    float* __restrict__ pivec, uint32_t* __restrict__ Wp,
    float* __restrict__ bias, uint32_t* __restrict__ Af)
{
  __shared__ float As[32][32];
  const int tid = threadIdx.x;       // 0..1023
  const int row = tid >> 5;          // 0..31
  const int col = tid & 31;          // 0..31

  {
    float v = tm[row * 32 + col];
    float m = v;
    #pragma unroll
    for (int mask = 16; mask; mask >>= 1) m = fmaxf(m, __shfl_xor(m, mask));
    float e = __expf(v - m);
    float s = e;
    #pragma unroll
    for (int mask = 16; mask; mask >>= 1) s += __shfl_xor(s, mask);
    As[row][col] = e / s;
  }

  if (tid < 32) {
    float v = sp[tid];
    float m = v;
    #pragma unroll
    for (int mask = 16; mask; mask >>= 1) m = fmaxf(m, __shfl_xor(m, mask));
    float e = __expf(v - m);
    float s = e;
    #pragma unroll
    for (int mask = 16; mask; mask >>= 1) s += __shfl_xor(s, mask);
    pivec[tid] = e / s;
  }

  #pragma unroll
  for (int hh = 0; hh < 2; ++hh) {
    int d = col + (hh << 5);             // 0..63
    float iv = __expf(-lv[row * 64 + d]);
    uint32_t w = cvt_pk_bf16(-0.5f * iv, mus[row * 64 + d] * iv);
    int kk = d >> 3, h2 = (d >> 2) & 1, j = d & 3;
    Wp[(((row << 1) + h2) * 8 + kk) * 4 + j] = w;
  }

  {
    float s2 = 0.f, slv = 0.f;
    #pragma unroll
    for (int h = 0; h < 2; ++h) {
      int d = col + h * 32;
      float m_ = mus[row * 64 + d];
      float l_ = lv[row * 64 + d];
      s2 = fmaf(m_ * m_, __expf(-l_), s2);
      slv += l_;
    }
    #pragma unroll
    for (int mask = 16; mask; mask >>= 1) {
      s2  += __shfl_xor(s2, mask);
      slv += __shfl_xor(slv, mask);
    }
    if (col == 0) bias[row] = -0.5f * (s2 + slv + (float)DD * LOG2PI);
  }

  __syncthreads();

  if (tid < 512) {
    int l = tid >> 3, s = tid & 7;
    int m = s >> 2, p = s & 3;
    int j = l & 31, hh = l >> 5;
    int r0 = 2 * p, r1 = r0 + 1;
    int s0 = (r0 & 3) + 8 * ((r0 >> 2) & 1) + 4 * hh + 16 * m;
    int s1 = (r1 & 3) + 8 * ((r1 >> 2) & 1) + 4 * hh + 16 * m;
    Af[(l << 3) + (m << 2) + p] = cvt_pk_bf16(As[s0][j], As[s1][j]);
  }
}

// ---------------- K2: FUSED emission + scan (R14-exact)
// Block = (subject b, 512-row superblock cb) = 32 chunks of 16.
// Emis phase: 4 waves x 17 windows (16 real + warmup overlap) -> blin in LDS
// (544 rows x 64 B, slot-XOR swizzle). Scan phase: wave 0, 32 chunks from LDS.
// blin NEVER touches HBM.
__global__ __launch_bounds__(256) void k_fused(
    const float* __restrict__ Xg,
    const uint32_t* __restrict__ Wp,
    const float* __restrict__ bias,
    const uint32_t* __restrict__ Af,
    const float* __restrict__ pivec,
    float* __restrict__ out,
    float* __restrict__ Mc)
{
  __shared__ uint32_t blinL[544 * 16];   // 34 KB
  __shared__ float KcL[32];
  const int tid = threadIdx.x;
  const int l   = tid & 63;
  const int wv  = tid >> 6;            // wave 0..3
  const int g   = blockIdx.x;          // 0..511
  const int b   = g >> 3;
  const int cb  = g & 7;
  const int t0  = cb << 9;             // superblock start t
  const int n   = l & 31;
  const int h   = l >> 5;

  // hoisted emis B-frags + bias
  uint4 wf[8];
  const uint4* wp4 = (const uint4*)(Wp + ((n << 1) + h) * 32);
  #pragma unroll
  for (int kk = 0; kk < 8; ++kk) wf[kk] = wp4[kk];
  const float bn = bias[n];

  // ---- emis phase: windows wi=0 (warmup overlap) .. 16
  for (int wi = wv; wi < 17; wi += 4) {
    if (cb == 0 && wi == 0) continue;            // chunk-0 clamp handles it
    const int wbase = t0 - 32 + (wi << 5);       // global t of window row 0
    const float* xr = Xg + (size_t)(b * TT + wbase + n) * DD + (h << 2);

    f32x16 acc;
    #pragma unroll
    for (int r = 0; r < 16; ++r) acc[r] = 0.0f;

    #pragma unroll
    for (int kk = 0; kk < 8; ++kk) {
      float4 x4 = *(const float4*)(xr + (kk << 3));
      uint4 au;
      au.x = cvt_pk_bf16(x4.x * x4.x, x4.x);
      au.y = cvt_pk_bf16(x4.y * x4.y, x4.y);
      au.z = cvt_pk_bf16(x4.z * x4.z, x4.z);
      au.w = cvt_pk_bf16(x4.w * x4.w, x4.w);
      bf16x8 af = __builtin_bit_cast(bf16x8, au);
      bf16x8 bf = __builtin_bit_cast(bf16x8, wf[kk]);
      acc = __builtin_amdgcn_mfma_f32_32x32x16_bf16(af, bf, acc, 0, 0, 0);
    }

    float lb[16];
    float m0 = -1e30f, m1 = -1e30f;
    #pragma unroll
    for (int r = 0; r < 16; ++r) {
      lb[r] = acc[r] + bn;
      if (r < 8) m0 = fmaxf(m0, lb[r]); else m1 = fmaxf(m1, lb[r]);
    }
    m0 = dpp_max64(m0);
    m1 = dpp_max64(m1);
    const float Km0 = __int_as_float(__builtin_amdgcn_readlane(__float_as_int(m0), 63));
    const float Km1 = __int_as_float(__builtin_amdgcn_readlane(__float_as_int(m1), 63));
    if (wi >= 1 && l == 0) {
      KcL[((wi - 1) << 1)]     = Km0;
      KcL[((wi - 1) << 1) + 1] = Km1;
    }

    const int rb = wi << 5;                      // LDS row of window row 0
    #pragma unroll
    for (int r = 0; r < 16; ++r) {
      float e = __expf(lb[r] - ((r < 8) ? Km0 : Km1));
      int nb = __builtin_amdgcn_update_dpp(0, __float_as_int(e), 0xB1, 0xF, 0xF, true); // lane^1
      uint32_t pk = cvt_pk_bf16(e, __int_as_float(nb));   // lo = even n, hi = odd n
      const int ldsrow = rb + (r & 3) + ((r >> 2) << 3) + (h << 2);
      if ((l & 1) == 0)
        blinL[ldsrow * 16 + ((n >> 1) ^ (((ldsrow >> 4) & 7) << 1))] = pk;
    }
  }
  __syncthreads();
  if (wv != 0) return;

  // ---- scan phase (wave 0 only): 32 chunks, lane col = chunk
  const int col = n;
  const int c   = (cb << 5) + col;               // chunk 0..255
  const bool isC0 = (cb == 0) && (col == 0);

  const uint4 af0u = *(const uint4*)(Af + (l << 3));
  const uint4 af1u = *(const uint4*)(Af + (l << 3) + 4);
  const bf16x8 af0 = __builtin_bit_cast(bf16x8, af0u);
  const bf16x8 af1 = __builtin_bit_cast(bf16x8, af1u);

  const float KcH = KcL[col];
  const int outbase = b * TT + (c << 4);

  f32x16 zv;
  #pragma unroll
  for (int r = 0; r < 16; ++r) zv[r] = 0.0f;

  float v[16];
  #pragma unroll
  for (int r = 0; r < 16; ++r) v[r] = 1.0f;
  float S = 0.0f, sPrev = 1.0f;

  #pragma unroll
  for (int q = 0; q < NSTEPS; ++q) {
    float sP = fmaxf(sPrev, FLT_MIN_NORM);
    int e = ((__float_as_int(sP) >> 23) & 0xFF) - 126;
    float rf = __int_as_float((127 - e) << 23);
    if (q >= WU) {
      float outv = __log2f(sP) * LN2F + S;
      if (q == WU) { if (h == 0) Mc[(b << 8) + c] = outv; }
      else         { if (h == 0) out[outbase + q - WU - 1] = outv; }
      S += KcH + (float)e * LN2F;
    } else {
      S += (float)e * LN2F;
    }

    // read b_t row from LDS (logical slots {h2,h2+1, +4, +8, +12})
    int ldsrow = 24 + (col << 4) + q;
    if (cb == 0 && ldsrow < 32) ldsrow = 32;     // chunk-0 clamp
    const int swz = ((ldsrow >> 4) & 7) << 1;
    const uint32_t* p = blinL + ldsrow * 16;
    const int h2 = h << 1;
    uint2 u0 = *(const uint2*)(p + (h2 ^ swz));
    uint2 u1 = *(const uint2*)(p + ((h2 + 4) ^ swz));
    uint2 u2 = *(const uint2*)(p + ((h2 + 8) ^ swz));
    uint2 u3 = *(const uint2*)(p + ((h2 + 12) ^ swz));
    uint32_t CUR[8];
    CUR[0] = u0.x; CUR[1] = u0.y; CUR[2] = u1.x; CUR[3] = u1.y;
    CUR[4] = u2.x; CUR[5] = u2.y; CUR[6] = u3.x; CUR[7] = u3.y;

    float vr[16];
    #pragma unroll
    for (int r = 0; r < 16; ++r) vr[r] = v[r] * rf;
    uint32_t p2[8];
    #pragma unroll
    for (int i = 0; i < 8; ++i) p2[i] = cvt_pk_bf16(vr[2*i], vr[2*i+1]);
    uint4 b0u; b0u.x = p2[0]; b0u.y = p2[1]; b0u.z = p2[2]; b0u.w = p2[3];
    uint4 b1u; b1u.x = p2[4]; b1u.y = p2[5]; b1u.z = p2[6]; b1u.w = p2[7];
    f32x16 acc = __builtin_amdgcn_mfma_f32_32x32x16_bf16(af0, __builtin_bit_cast(bf16x8, b0u), zv, 0, 0, 0);
    acc = __builtin_amdgcn_mfma_f32_32x32x16_bf16(af1, __builtin_bit_cast(bf16x8, b1u), acc, 0, 0, 0);

    #pragma unroll
    for (int i = 0; i < 8; ++i) {
      float blo = __int_as_float(CUR[i] << 16);
      float bhi = __int_as_float(CUR[i] & 0xFFFF0000u);
      float d0 = acc[2*i], d1 = acc[2*i+1];
      if (q == WU) { if (isC0) { d0 = vr[2*i]; d1 = vr[2*i+1]; } }
      v[2*i]   = d0 * blo;
      v[2*i+1] = d1 * bhi;
    }
    if (q == WU - 1) {
      if (isC0) {
        #pragma unroll
        for (int r = 0; r < 16; ++r)
          v[r] = pivec[(r & 3) + 8 * ((r >> 2) & 1) + (h << 2) + ((r >> 3) << 4)];
        S = 0.0f;
      }
    }
    float s8[8];
    #pragma unroll
    for (int i = 0; i < 8; ++i) s8[i] = v[2*i] + v[2*i+1];
    float s4a = s8[0] + s8[1], s4b = s8[2] + s8[3];
    float s4c = s8[4] + s8[5], s4d = s8[6] + s8[7];
    float s = (s4a + s4b) + (s4c + s4d);
    s += __shfl_xor(s, 32);
    sPrev = s;
  }

  {
    float sP = fmaxf(sPrev, FLT_MIN_NORM);
    if (h == 0) out[outbase + CL - 1] = __log2f(sP) * LN2F + S;
  }
}

// ---------------- K3: FUSED stitch + add (one block per subject)
__global__ __launch_bounds__(256) void k_post(
    float* __restrict__ out, const float* __restrict__ Mcc)
{
  __shared__ float DeltaL[256];
  __shared__ float wsum[4];
  const int b  = blockIdx.x;
  const int c  = threadIdx.x;     // 0..255 (4 waves)
  const int wv = c >> 6, ln = c & 63;
  float term = 0.0f;
  if (c > 0) term = out[b * TT + (c << 4) - 1] - Mcc[(b << 8) + c];
  for (int off = 1; off < 64; off <<= 1) {
    float up = __shfl_up(term, off);
    if (ln >= off) term += up;
  }
  if (ln == 63) wsum[wv] = term;
  __syncthreads();
  float add = 0.0f;
  for (int i = 0; i < wv; ++i) add += wsum[i];
  DeltaL[c] = term + add;
  __syncthreads();
  #pragma unroll
  for (int t = c; t < TT; t += 256)
    out[b * TT + t] += DeltaL[t >> 4];
}

extern "C" void kernel_launch(void* const* d_in, const int* in_sizes, int n_in,
                              void* d_out, int out_size, void* d_ws, size_t ws_size,
                              hipStream_t stream) {
  const float* X   = (const float*)d_in[0];
  const float* tm  = (const float*)d_in[1];
  const float* sp  = (const float*)d_in[2];
  const float* mus = (const float*)d_in[3];
  const float* lv  = (const float*)d_in[4];
  float* out = (float*)d_out;

  char* ws = (char*)d_ws;
  size_t off = 0;
  float* Mcc   = (float*)(ws + off); off += (size_t)BB * CH * 4;
  float* pivec = (float*)(ws + off); off += 256;
  uint32_t* Wp = (uint32_t*)(ws + off); off += (size_t)2048 * 4;
  float* bias  = (float*)(ws + off); off += 256;
  uint32_t* Af = (uint32_t*)(ws + off); off += (size_t)512 * 4;

  k_pre<<<dim3(1), dim3(1024), 0, stream>>>(tm, sp, mus, lv, pivec, Wp, bias, Af);
  k_fused<<<dim3(512), dim3(256), 0, stream>>>(X, Wp, bias, Af, pivec, out, Mcc);
  k_post<<<dim3(BB), dim3(256), 0, stream>>>(out, Mcc);
}